// Round 16
// baseline (181.544 us; speedup 1.0000x reference)
//
#include <hip/hip_runtime.h>

#define N_NODES 10000
#define HID 512
#define MPAD 10112          // 158 * 64
#define N_GRAPHS 64
#define N_CLASSES 10

typedef __bf16 bf16_t;
typedef __bf16 bf16x8 __attribute__((ext_vector_type(8)));
typedef float  f32x4  __attribute__((ext_vector_type(4)));

// ---------------------------------------------------------------------------
// async global->LDS 16B copy (gfx950). LDS dest is wave-uniform base + lane*16;
// our chunk->thread mapping is linear so per-lane dst pointers satisfy that.
// ---------------------------------------------------------------------------
__device__ __forceinline__ void gload16(const bf16_t* g, bf16_t* l) {
    __builtin_amdgcn_global_load_lds(
        (const __attribute__((address_space(1))) void*)g,
        (__attribute__((address_space(3))) void*)l,
        16, 0, 0);
}

// ---------------------------------------------------------------------------
// zero_k: cnt, cur, xh pad rows, pooled — one dispatch replaces the memsets
// ---------------------------------------------------------------------------
__global__ void zero_k(int* __restrict__ cnt, int* __restrict__ cur,
                       bf16_t* __restrict__ xh_pad, float* __restrict__ pooled) {
    int i = blockIdx.x * 256 + threadIdx.x;          // grid 40*256 = 10240
    if (i < N_NODES) { cnt[i] = 0; cur[i] = 0; }
    const int PCH = (MPAD - N_NODES) * HID / 8;      // 7168 16B-chunks
    uint4 z = {0, 0, 0, 0};
    if (i < PCH) *(uint4*)&xh_pad[i * 8] = z;
    if (i < N_GRAPHS * HID / 4) *(uint4*)&pooled[i * 4] = z;
}

// ---------------------------------------------------------------------------
// setup_k: conv_x (blocks 0..2499) + conv_w LDS-transpose (2500..2691)
//        + count_deg (2692..). conv_w: 64x64 fp32 tile through LDS —
// coalesced 256B reads / 128B bf16 writes; [64][65] pad -> 2-way (free).
// ---------------------------------------------------------------------------
#define CVX_B 2500
#define TRW_B 192           // 3 layers * 64 tiles of 64x64
__global__ void setup_k(const float* __restrict__ x,
                        bf16_t* __restrict__ xh,
                        const float* __restrict__ W, bf16_t* __restrict__ whT,
                        const int* __restrict__ ecol, int* __restrict__ cnt, int E) {
    __shared__ float tile[64][65];
    int b = blockIdx.x, t = threadIdx.x;
    if (b < CVX_B) {
        // x (fp32) -> bf16 (pure-bf16 GEMM)
        int idx = (b * 256 + t) * 8;                 // < N_NODES*HID
        f32x4 v0 = *(const f32x4*)&x[idx];
        f32x4 v1 = *(const f32x4*)&x[idx + 4];
        float v[8] = {v0[0], v0[1], v0[2], v0[3], v1[0], v1[1], v1[2], v1[3]};
        bf16x8 hi;
#pragma unroll
        for (int j = 0; j < 8; ++j) hi[j] = (bf16_t)v[j];
        *(bf16x8*)&xh[idx] = hi;
    } else if (b < CVX_B + TRW_B) {
        // W [3][512][512] (W[l][k][j]) -> transposed bf16: WT[l][j][k]
        int tt  = b - CVX_B;
        int lyr = tt >> 6;
        int rem = tt & 63;
        int k0  = (rem >> 3) * 64;
        int j0  = (rem & 7) * 64;
        const float* Wl = W + ((size_t)lyr << 18);
        int r = t >> 6, c = t & 63;                  // wave row / lane col
#pragma unroll
        for (int i = 0; i < 16; ++i) {               // read: consecutive j
            int row = r + i * 4;
            tile[row][c] = Wl[(size_t)(k0 + row) * 512 + j0 + c];
        }
        __syncthreads();
        bf16_t* Ol = whT + ((size_t)lyr << 18);
#pragma unroll
        for (int i = 0; i < 16; ++i) {               // write: consecutive k
            int row = r + i * 4;                     // j - j0
            Ol[(size_t)(j0 + row) * 512 + k0 + c] = (bf16_t)tile[c][row];
        }
    } else {
        int e = (b - CVX_B - TRW_B) * 256 + t;
        if (e < E) atomicAdd(&cnt[ecol[e]], 1);
    }
}

// scan (exclusive prefix over cnt -> off) + dinv fused (reads cnt anyway)
__global__ __launch_bounds__(1024) void scan_k(const int* __restrict__ cnt,
                                               int* __restrict__ off,
                                               float* __restrict__ dinv) {
    __shared__ int s[1024];
    int t = threadIdx.x;
    int base = t * 10;
    int loc[10];
    int sum = 0;
#pragma unroll
    for (int j = 0; j < 10; ++j) {
        int n = base + j;
        int v = (n < N_NODES) ? cnt[n] : 0;
        if (n < N_NODES) dinv[n] = rsqrtf(1.0f + (float)v);  // +1 self-loop
        loc[j] = sum;
        sum += v;
    }
    s[t] = sum;
    __syncthreads();
    for (int o = 1; o < 1024; o <<= 1) {
        int v = (t >= o) ? s[t - o] : 0;
        __syncthreads();
        s[t] += v;
        __syncthreads();
    }
    int pre = (t > 0) ? s[t - 1] : 0;
#pragma unroll
    for (int j = 0; j < 10; ++j) {
        int n = base + j;
        if (n <= N_NODES) off[n] = pre + loc[j];
    }
}

// packed edge record: .x = src index, .y = float bits of weight
__global__ void scatter_k(const int* __restrict__ row, const int* __restrict__ col,
                          const int* __restrict__ off, int* __restrict__ cursor,
                          const float* __restrict__ dinv,
                          int2* __restrict__ epk, int E) {
    int e = blockIdx.x * 256 + threadIdx.x;
    if (e >= E) return;
    int c = col[e], r = row[e];
    int p = off[c] + atomicAdd(&cursor[c], 1);
    float w = dinv[r] * dinv[c];
    epk[p] = make_int2(r, __float_as_int(w));
}

// ---------------------------------------------------------------------------
// GEMM: hh[MPAD][512] = bf16( xh @ Wh )  — pure bf16 MFMA.
// 64x128 tile, 4 waves (2x2), 32x64/wave, BK=32, global_load_lds, 2-buf dbuf.
// XCD-aware bijective swizzle (T1): 632 = 8*79 exactly; XCD x gets tiles
// [x*79,(x+1)*79) = ~20 consecutive M-panels x 4 N-tiles -> each A-panel
// L3-fetched once into ONE XCD L2 and reused 4x (was: 4 XCDs, 4x L3 traffic).
// ---------------------------------------------------------------------------
__global__ __launch_bounds__(256) void gemm3(
    const bf16_t* __restrict__ xh,
    const bf16_t* __restrict__ wh,   // [512][512] = W^T[j][k]
    bf16_t* __restrict__ hh)
{
    __shared__ alignas(16) bf16_t sAh[2][64 * 32];
    __shared__ alignas(16) bf16_t sBh[2][128 * 32];

    const int t  = threadIdx.x;
    const int l  = t & 63;
    const int wv = t >> 6;
    const int wr = wv >> 1;   // 0..1: 32-row half of M-tile
    const int wc = wv & 1;    // 0..1: 64-col half of N-tile

    // bijective XCD swizzle: dispatch id -> tile id
    const int tile = (blockIdx.x & 7) * 79 + (blockIdx.x >> 3);   // 0..631
    const int n0 = (tile & 3) * 128;        // N-tile fastest within an XCD run
    const int m0 = (tile >> 2) * 64;

    f32x4 acc[2][4];
#pragma unroll
    for (int m = 0; m < 2; ++m)
#pragma unroll
        for (int n = 0; n < 4; ++n) acc[m][n] = (f32x4){0.f, 0.f, 0.f, 0.f};

    const int lr  = l & 15;
    const int kgr = (l >> 4) * 8;        // k-group start within BK=32
    const int srow = t >> 2;             // staging row 0..63
    const int sce  = (t & 3) * 8;        // staging element offset within row

    auto stage = [&](int buf, int kk) {
        size_t gA  = (size_t)(m0 + srow) * HID + kk + sce;
        size_t gB0 = (size_t)(n0 + srow) * HID + kk + sce;
        size_t gB1 = (size_t)(n0 + 64 + srow) * HID + kk + sce;
        gload16(&xh[gA],  &sAh[buf][t * 8]);
        gload16(&wh[gB0], &sBh[buf][t * 8]);
        gload16(&wh[gB1], &sBh[buf][(t + 256) * 8]);
    };

    stage(0, 0);
    __syncthreads();           // buf0 ready

    int cur = 0;
    for (int kk = 0; kk < HID; kk += 32) {
        if (kk + 32 < HID) stage(cur ^ 1, kk + 32);   // issue next-tile loads

        bf16x8 ah[2], bh[4];
#pragma unroll
        for (int m = 0; m < 2; ++m) {
            int row = wr * 32 + m * 16 + lr;
            ah[m] = *(const bf16x8*)&sAh[cur][row * 32 + kgr];
        }
#pragma unroll
        for (int n = 0; n < 4; ++n) {
            int col = wc * 64 + n * 16 + lr;
            bh[n] = *(const bf16x8*)&sBh[cur][col * 32 + kgr];
        }
#pragma unroll
        for (int m = 0; m < 2; ++m)
#pragma unroll
            for (int n = 0; n < 4; ++n)
                acc[m][n] = __builtin_amdgcn_mfma_f32_16x16x32_bf16(ah[m], bh[n], acc[m][n], 0, 0, 0);

        __syncthreads();
        cur ^= 1;
    }

    // C/D layout (m89-verified): col = l&15, row = (l>>4)*4 + r
    const int rq = (l >> 4) * 4;
#pragma unroll
    for (int m = 0; m < 2; ++m) {
        int row = m0 + wr * 32 + m * 16 + rq;
#pragma unroll
        for (int n = 0; n < 4; ++n) {
            int col = n0 + wc * 64 + n * 16 + lr;
#pragma unroll
            for (int r = 0; r < 4; ++r)
                hh[(size_t)(row + r) * HID + col] = (bf16_t)acc[m][n][r];
        }
    }
}

// ---------------------------------------------------------------------------
// Aggregation: out[n] = relu( sum_{e->n} w_e * hh[src_e] + dinv[n]^2 * hh[n] + b )
// TWO waves per node (round-15 form, at floor), 2 nodes per block,
// bank-clean combine. Pooling separate (round-14 atomics refuted).
// ---------------------------------------------------------------------------
template <bool LAST>
__global__ __launch_bounds__(256) void agg_k(
    const bf16_t* __restrict__ hh, const int* __restrict__ off,
    const int2* __restrict__ epk,
    const float* __restrict__ dinv, const float* __restrict__ bias,
    bf16_t* __restrict__ xh, float* __restrict__ x3)
{
    __shared__ float red[2][HID];
    int slot = threadIdx.x >> 7;            // node within block (0..1)
    int w    = (threadIdx.x >> 6) & 1;      // wave half for this node
    int node = blockIdx.x * 2 + slot;       // grid 5000 = N_NODES/2 exact
    int l  = threadIdx.x & 63;
    int c0 = l * 8;

    float a[8];
    int e0 = off[node], e1 = off[node + 1];
    int mid = (e0 + e1 + 1) >> 1;           // wave0: [e0,mid)  wave1: [mid,e1)
    int es = w ? mid : e0;
    int ee = w ? e1 : mid;

    if (w == 0) {
        float dn = dinv[node];
        float sw = dn * dn;
        bf16x8 sv = *(const bf16x8*)&hh[(size_t)node * HID + c0];
#pragma unroll
        for (int j = 0; j < 8; ++j) a[j] = (float)sv[j] * sw;
    } else {
#pragma unroll
        for (int j = 0; j < 8; ++j) a[j] = 0.f;
    }

    int e = es;
    for (; e + 4 <= ee; e += 4) {
        int4 p0 = *(const int4*)&epk[e];
        int4 p1 = *(const int4*)&epk[e + 2];
        bf16x8 v0 = *(const bf16x8*)&hh[(size_t)p0.x * HID + c0];
        bf16x8 v1 = *(const bf16x8*)&hh[(size_t)p0.z * HID + c0];
        bf16x8 v2 = *(const bf16x8*)&hh[(size_t)p1.x * HID + c0];
        bf16x8 v3 = *(const bf16x8*)&hh[(size_t)p1.z * HID + c0];
        float w0 = __int_as_float(p0.y), w1 = __int_as_float(p0.w);
        float w2 = __int_as_float(p1.y), w3 = __int_as_float(p1.w);
#pragma unroll
        for (int j = 0; j < 8; ++j) {
            a[j] += (float)v0[j] * w0 + (float)v1[j] * w1
                  + (float)v2[j] * w2 + (float)v3[j] * w3;
        }
    }
    for (; e < ee; ++e) {
        int2 ed = epk[e];
        float ww = __int_as_float(ed.y);
        bf16x8 v = *(const bf16x8*)&hh[(size_t)ed.x * HID + c0];
#pragma unroll
        for (int j = 0; j < 8; ++j) a[j] += (float)v[j] * ww;
    }

    if (w == 1) {
#pragma unroll
        for (int j = 0; j < 8; ++j) red[slot][j * 64 + l] = a[j];   // bank-clean
    }
    __syncthreads();
    if (w == 0) {
#pragma unroll
        for (int j = 0; j < 8; ++j) {
            a[j] += red[slot][j * 64 + l] + bias[c0 + j];
            if (a[j] < 0.f) a[j] = 0.f;
        }
        if (LAST) {
            f32x4 o0 = {a[0], a[1], a[2], a[3]};
            f32x4 o1 = {a[4], a[5], a[6], a[7]};
            *(f32x4*)&x3[(size_t)node * HID + c0]     = o0;
            *(f32x4*)&x3[(size_t)node * HID + c0 + 4] = o1;
        } else {
            bf16x8 hi;
#pragma unroll
            for (int j = 0; j < 8; ++j) hi[j] = (bf16_t)a[j];
            *(bf16x8*)&xh[(size_t)node * HID + c0] = hi;
        }
    }
}

// ---------------------------------------------------------------------------
// Pooling: pooled[g][c] += x3[n][c] for batch[n]==g (batch sorted, run-flush)
// ---------------------------------------------------------------------------
__global__ void pool_k(const float* __restrict__ x3, const int* __restrict__ batch,
                       float* __restrict__ pooled) {
    int t  = threadIdx.x;            // 256: cols t and t+256
    int n0 = blockIdx.x * 20;
    int nend = min(n0 + 20, N_NODES);
    float acc0 = 0.f, acc1 = 0.f;
    int cur = -1;
    for (int n = n0; n < nend; ++n) {
        int g = batch[n];
        if (g != cur) {
            if (cur >= 0) {
                atomicAdd(&pooled[cur * HID + t], acc0);
                atomicAdd(&pooled[cur * HID + t + 256], acc1);
            }
            cur = g; acc0 = 0.f; acc1 = 0.f;
        }
        acc0 += x3[(size_t)n * HID + t];
        acc1 += x3[(size_t)n * HID + t + 256];
    }
    if (cur >= 0) {
        atomicAdd(&pooled[cur * HID + t], acc0);
        atomicAdd(&pooled[cur * HID + t + 256], acc1);
    }
}

// ---------------------------------------------------------------------------
// Head: logits = pooled @ lin_w + lin_b ; log_softmax. One wave per graph.
// ---------------------------------------------------------------------------
__global__ __launch_bounds__(64) void head_k(const float* __restrict__ pooled,
                                             const float* __restrict__ lw,
                                             const float* __restrict__ lb,
                                             float* __restrict__ out) {
    int g = blockIdx.x, l = threadIdx.x;
    float lg[10];
#pragma unroll
    for (int c = 0; c < N_CLASSES; ++c) {
        float s = 0.f;
        for (int k = l; k < HID; k += 64) s += pooled[g * HID + k] * lw[k * N_CLASSES + c];
        for (int o2 = 32; o2 > 0; o2 >>= 1) s += __shfl_down(s, o2);
        lg[c] = s;
    }
    if (l == 0) {
        float mx = -1e30f;
#pragma unroll
        for (int c = 0; c < N_CLASSES; ++c) { lg[c] += lb[c]; mx = fmaxf(mx, lg[c]); }
        float se = 0.f;
#pragma unroll
        for (int c = 0; c < N_CLASSES; ++c) se += expf(lg[c] - mx);
        float lse = logf(se);
#pragma unroll
        for (int c = 0; c < N_CLASSES; ++c) out[g * N_CLASSES + c] = lg[c] - mx - lse;
    }
}

// ---------------------------------------------------------------------------
extern "C" void kernel_launch(void* const* d_in, const int* in_sizes, int n_in,
                              void* d_out, int out_size, void* d_ws, size_t ws_size,
                              hipStream_t stream) {
    const float* x     = (const float*)d_in[0];
    const int*   ei    = (const int*)d_in[1];
    const int*   batch = (const int*)d_in[2];
    const float* Ws    = (const float*)d_in[3];
    const float* bs    = (const float*)d_in[4];
    const float* lw    = (const float*)d_in[5];
    const float* lb    = (const float*)d_in[6];
    float*       out   = (float*)d_out;
    const int E = in_sizes[1] / 2;
    const int* erow = ei;       // edge_index[0] = source
    const int* ecol = ei + E;   // edge_index[1] = target (aggregation index)

    char* p = (char*)d_ws;
    auto take = [&](size_t bytes) {
        char* q = p;
        p += (bytes + 255) & ~(size_t)255;
        return q;
    };
    bf16_t* xh    = (bf16_t*)take((size_t)MPAD * HID * 2);
    bf16_t* hh    = (bf16_t*)take((size_t)MPAD * HID * 2);
    float*  x3    = (float*) take((size_t)N_NODES * HID * 4);
    bf16_t* whT   = (bf16_t*)take((size_t)3 * HID * HID * 2);
    float*  dinv  = (float*) take((size_t)N_NODES * 4);
    int*    cnt   = (int*)   take((size_t)N_NODES * 4);
    int*    off   = (int*)   take((size_t)(N_NODES + 1) * 4);
    int*    cur   = (int*)   take((size_t)N_NODES * 4);
    int2*   epk   = (int2*)  take((size_t)E * 8 + 64);   // +pad for int4 tail read
    float*  pooled= (float*) take((size_t)N_GRAPHS * HID * 4);

    const int cdeg_b = (E + 255) / 256;
    zero_k<<<40, 256, 0, stream>>>(cnt, cur, xh + (size_t)N_NODES * HID, pooled);
    setup_k<<<CVX_B + TRW_B + cdeg_b, 256, 0, stream>>>(
        x, xh, Ws, whT, ecol, cnt, E);
    scan_k<<<1, 1024, 0, stream>>>(cnt, off, dinv);
    scatter_k<<<cdeg_b, 256, 0, stream>>>(erow, ecol, off, cur, dinv, epk, E);

    for (int lyr = 0; lyr < 3; ++lyr) {
        gemm3<<<632, 256, 0, stream>>>(
            xh, whT + (size_t)lyr * HID * HID, hh);
        if (lyr < 2)
            agg_k<false><<<N_NODES / 2, 256, 0, stream>>>(
                hh, off, epk, dinv, bs + lyr * HID, xh, nullptr);
        else
            agg_k<true><<<N_NODES / 2, 256, 0, stream>>>(
                hh, off, epk, dinv, bs + lyr * HID, nullptr, x3);
    }
    pool_k<<<500, 256, 0, stream>>>(x3, batch, pooled);
    head_k<<<N_GRAPHS, 64, 0, stream>>>(pooled, lw, lb, out);
}

// Round 17
// 178.693 us; speedup vs baseline: 1.0160x; 1.0160x over previous
//
#include <hip/hip_runtime.h>

#define N_NODES 10000
#define HID 512
#define MPAD 10112          // 158 * 64
#define N_GRAPHS 64
#define N_CLASSES 10

typedef __bf16 bf16_t;
typedef __bf16 bf16x8 __attribute__((ext_vector_type(8)));
typedef float  f32x4  __attribute__((ext_vector_type(4)));

// ---------------------------------------------------------------------------
// async global->LDS 16B copy (gfx950). LDS dest is wave-uniform base + lane*16;
// our chunk->thread mapping is linear so per-lane dst pointers satisfy that.
// ---------------------------------------------------------------------------
__device__ __forceinline__ void gload16(const bf16_t* g, bf16_t* l) {
    __builtin_amdgcn_global_load_lds(
        (const __attribute__((address_space(1))) void*)g,
        (__attribute__((address_space(3))) void*)l,
        16, 0, 0);
}

// ---------------------------------------------------------------------------
// zero_k: cnt, cur, xh pad rows, pooled — one dispatch replaces the memsets
// ---------------------------------------------------------------------------
__global__ void zero_k(int* __restrict__ cnt, int* __restrict__ cur,
                       bf16_t* __restrict__ xh_pad, float* __restrict__ pooled) {
    int i = blockIdx.x * 256 + threadIdx.x;          // grid 40*256 = 10240
    if (i < N_NODES) { cnt[i] = 0; cur[i] = 0; }
    const int PCH = (MPAD - N_NODES) * HID / 8;      // 7168 16B-chunks
    uint4 z = {0, 0, 0, 0};
    if (i < PCH) *(uint4*)&xh_pad[i * 8] = z;
    if (i < N_GRAPHS * HID / 4) *(uint4*)&pooled[i * 4] = z;
}

// ---------------------------------------------------------------------------
// setup_k: conv_x (blocks 0..2499) + conv_w LDS-transpose (2500..2691)
//        + count_deg (2692..). conv_w: 64x64 fp32 tile through LDS —
// coalesced 256B reads / 128B bf16 writes; [64][65] pad -> 2-way (free).
// ---------------------------------------------------------------------------
#define CVX_B 2500
#define TRW_B 192           // 3 layers * 64 tiles of 64x64
__global__ void setup_k(const float* __restrict__ x,
                        bf16_t* __restrict__ xh,
                        const float* __restrict__ W, bf16_t* __restrict__ whT,
                        const int* __restrict__ ecol, int* __restrict__ cnt, int E) {
    __shared__ float tile[64][65];
    int b = blockIdx.x, t = threadIdx.x;
    if (b < CVX_B) {
        // x (fp32) -> bf16 (pure-bf16 GEMM)
        int idx = (b * 256 + t) * 8;                 // < N_NODES*HID
        f32x4 v0 = *(const f32x4*)&x[idx];
        f32x4 v1 = *(const f32x4*)&x[idx + 4];
        float v[8] = {v0[0], v0[1], v0[2], v0[3], v1[0], v1[1], v1[2], v1[3]};
        bf16x8 hi;
#pragma unroll
        for (int j = 0; j < 8; ++j) hi[j] = (bf16_t)v[j];
        *(bf16x8*)&xh[idx] = hi;
    } else if (b < CVX_B + TRW_B) {
        // W [3][512][512] (W[l][k][j]) -> transposed bf16: WT[l][j][k]
        int tt  = b - CVX_B;
        int lyr = tt >> 6;
        int rem = tt & 63;
        int k0  = (rem >> 3) * 64;
        int j0  = (rem & 7) * 64;
        const float* Wl = W + ((size_t)lyr << 18);
        int r = t >> 6, c = t & 63;                  // wave row / lane col
#pragma unroll
        for (int i = 0; i < 16; ++i) {               // read: consecutive j
            int row = r + i * 4;
            tile[row][c] = Wl[(size_t)(k0 + row) * 512 + j0 + c];
        }
        __syncthreads();
        bf16_t* Ol = whT + ((size_t)lyr << 18);
#pragma unroll
        for (int i = 0; i < 16; ++i) {               // write: consecutive k
            int row = r + i * 4;                     // j - j0
            Ol[(size_t)(j0 + row) * 512 + k0 + c] = (bf16_t)tile[c][row];
        }
    } else {
        int e = (b - CVX_B - TRW_B) * 256 + t;
        if (e < E) atomicAdd(&cnt[ecol[e]], 1);
    }
}

// scan (exclusive prefix over cnt -> off) + dinv fused (reads cnt anyway)
__global__ __launch_bounds__(1024) void scan_k(const int* __restrict__ cnt,
                                               int* __restrict__ off,
                                               float* __restrict__ dinv) {
    __shared__ int s[1024];
    int t = threadIdx.x;
    int base = t * 10;
    int loc[10];
    int sum = 0;
#pragma unroll
    for (int j = 0; j < 10; ++j) {
        int n = base + j;
        int v = (n < N_NODES) ? cnt[n] : 0;
        if (n < N_NODES) dinv[n] = rsqrtf(1.0f + (float)v);  // +1 self-loop
        loc[j] = sum;
        sum += v;
    }
    s[t] = sum;
    __syncthreads();
    for (int o = 1; o < 1024; o <<= 1) {
        int v = (t >= o) ? s[t - o] : 0;
        __syncthreads();
        s[t] += v;
        __syncthreads();
    }
    int pre = (t > 0) ? s[t - 1] : 0;
#pragma unroll
    for (int j = 0; j < 10; ++j) {
        int n = base + j;
        if (n <= N_NODES) off[n] = pre + loc[j];
    }
}

// packed edge record: .x = src index, .y = float bits of weight
__global__ void scatter_k(const int* __restrict__ row, const int* __restrict__ col,
                          const int* __restrict__ off, int* __restrict__ cursor,
                          const float* __restrict__ dinv,
                          int2* __restrict__ epk, int E) {
    int e = blockIdx.x * 256 + threadIdx.x;
    if (e >= E) return;
    int c = col[e], r = row[e];
    int p = off[c] + atomicAdd(&cursor[c], 1);
    float w = dinv[r] * dinv[c];
    epk[p] = make_int2(r, __float_as_int(w));
}

// ---------------------------------------------------------------------------
// GEMM: hh[MPAD][512] = bf16( xh @ Wh )  — pure bf16 MFMA.
// 64x128 tile, 4 waves (2x2), 32x64/wave, BK=32, global_load_lds, 2-buf dbuf.
// grid (4,158) N-fastest — round-15 best config (XCD swizzle was null, r16).
// ---------------------------------------------------------------------------
__global__ __launch_bounds__(256) void gemm3(
    const bf16_t* __restrict__ xh,
    const bf16_t* __restrict__ wh,   // [512][512] = W^T[j][k]
    bf16_t* __restrict__ hh)
{
    __shared__ alignas(16) bf16_t sAh[2][64 * 32];
    __shared__ alignas(16) bf16_t sBh[2][128 * 32];

    const int t  = threadIdx.x;
    const int l  = t & 63;
    const int wv = t >> 6;
    const int wr = wv >> 1;   // 0..1: 32-row half of M-tile
    const int wc = wv & 1;    // 0..1: 64-col half of N-tile
    const int n0 = blockIdx.x * 128;
    const int m0 = blockIdx.y * 64;

    f32x4 acc[2][4];
#pragma unroll
    for (int m = 0; m < 2; ++m)
#pragma unroll
        for (int n = 0; n < 4; ++n) acc[m][n] = (f32x4){0.f, 0.f, 0.f, 0.f};

    const int lr  = l & 15;
    const int kgr = (l >> 4) * 8;        // k-group start within BK=32
    const int srow = t >> 2;             // staging row 0..63
    const int sce  = (t & 3) * 8;        // staging element offset within row

    auto stage = [&](int buf, int kk) {
        size_t gA  = (size_t)(m0 + srow) * HID + kk + sce;
        size_t gB0 = (size_t)(n0 + srow) * HID + kk + sce;
        size_t gB1 = (size_t)(n0 + 64 + srow) * HID + kk + sce;
        gload16(&xh[gA],  &sAh[buf][t * 8]);
        gload16(&wh[gB0], &sBh[buf][t * 8]);
        gload16(&wh[gB1], &sBh[buf][(t + 256) * 8]);
    };

    stage(0, 0);
    __syncthreads();           // buf0 ready

    int cur = 0;
    for (int kk = 0; kk < HID; kk += 32) {
        if (kk + 32 < HID) stage(cur ^ 1, kk + 32);   // issue next-tile loads

        bf16x8 ah[2], bh[4];
#pragma unroll
        for (int m = 0; m < 2; ++m) {
            int row = wr * 32 + m * 16 + lr;
            ah[m] = *(const bf16x8*)&sAh[cur][row * 32 + kgr];
        }
#pragma unroll
        for (int n = 0; n < 4; ++n) {
            int col = wc * 64 + n * 16 + lr;
            bh[n] = *(const bf16x8*)&sBh[cur][col * 32 + kgr];
        }
#pragma unroll
        for (int m = 0; m < 2; ++m)
#pragma unroll
            for (int n = 0; n < 4; ++n)
                acc[m][n] = __builtin_amdgcn_mfma_f32_16x16x32_bf16(ah[m], bh[n], acc[m][n], 0, 0, 0);

        __syncthreads();
        cur ^= 1;
    }

    // C/D layout (m89-verified): col = l&15, row = (l>>4)*4 + r
    const int rq = (l >> 4) * 4;
#pragma unroll
    for (int m = 0; m < 2; ++m) {
        int row = m0 + wr * 32 + m * 16 + rq;
#pragma unroll
        for (int n = 0; n < 4; ++n) {
            int col = n0 + wc * 64 + n * 16 + lr;
#pragma unroll
            for (int r = 0; r < 4; ++r)
                hh[(size_t)(row + r) * HID + col] = (bf16_t)acc[m][n][r];
        }
    }
}

// ---------------------------------------------------------------------------
// Aggregation: out[n] = relu( sum_{e->n} w_e * hh[src_e] + dinv[n]^2 * hh[n] + b )
// TWO waves per node, 2 nodes per block, bank-clean combine (round-15 form).
// ---------------------------------------------------------------------------
template <bool LAST>
__global__ __launch_bounds__(256) void agg_k(
    const bf16_t* __restrict__ hh, const int* __restrict__ off,
    const int2* __restrict__ epk,
    const float* __restrict__ dinv, const float* __restrict__ bias,
    bf16_t* __restrict__ xh, float* __restrict__ x3)
{
    __shared__ float red[2][HID];
    int slot = threadIdx.x >> 7;            // node within block (0..1)
    int w    = (threadIdx.x >> 6) & 1;      // wave half for this node
    int node = blockIdx.x * 2 + slot;       // grid 5000 = N_NODES/2 exact
    int l  = threadIdx.x & 63;
    int c0 = l * 8;

    float a[8];
    int e0 = off[node], e1 = off[node + 1];
    int mid = (e0 + e1 + 1) >> 1;           // wave0: [e0,mid)  wave1: [mid,e1)
    int es = w ? mid : e0;
    int ee = w ? e1 : mid;

    if (w == 0) {
        float dn = dinv[node];
        float sw = dn * dn;
        bf16x8 sv = *(const bf16x8*)&hh[(size_t)node * HID + c0];
#pragma unroll
        for (int j = 0; j < 8; ++j) a[j] = (float)sv[j] * sw;
    } else {
#pragma unroll
        for (int j = 0; j < 8; ++j) a[j] = 0.f;
    }

    int e = es;
    for (; e + 4 <= ee; e += 4) {
        int4 p0 = *(const int4*)&epk[e];
        int4 p1 = *(const int4*)&epk[e + 2];
        bf16x8 v0 = *(const bf16x8*)&hh[(size_t)p0.x * HID + c0];
        bf16x8 v1 = *(const bf16x8*)&hh[(size_t)p0.z * HID + c0];
        bf16x8 v2 = *(const bf16x8*)&hh[(size_t)p1.x * HID + c0];
        bf16x8 v3 = *(const bf16x8*)&hh[(size_t)p1.z * HID + c0];
        float w0 = __int_as_float(p0.y), w1 = __int_as_float(p0.w);
        float w2 = __int_as_float(p1.y), w3 = __int_as_float(p1.w);
#pragma unroll
        for (int j = 0; j < 8; ++j) {
            a[j] += (float)v0[j] * w0 + (float)v1[j] * w1
                  + (float)v2[j] * w2 + (float)v3[j] * w3;
        }
    }
    for (; e < ee; ++e) {
        int2 ed = epk[e];
        float ww = __int_as_float(ed.y);
        bf16x8 v = *(const bf16x8*)&hh[(size_t)ed.x * HID + c0];
#pragma unroll
        for (int j = 0; j < 8; ++j) a[j] += (float)v[j] * ww;
    }

    if (w == 1) {
#pragma unroll
        for (int j = 0; j < 8; ++j) red[slot][j * 64 + l] = a[j];   // bank-clean
    }
    __syncthreads();
    if (w == 0) {
#pragma unroll
        for (int j = 0; j < 8; ++j) {
            a[j] += red[slot][j * 64 + l] + bias[c0 + j];
            if (a[j] < 0.f) a[j] = 0.f;
        }
        if (LAST) {
            f32x4 o0 = {a[0], a[1], a[2], a[3]};
            f32x4 o1 = {a[4], a[5], a[6], a[7]};
            *(f32x4*)&x3[(size_t)node * HID + c0]     = o0;
            *(f32x4*)&x3[(size_t)node * HID + c0 + 4] = o1;
        } else {
            bf16x8 hi;
#pragma unroll
            for (int j = 0; j < 8; ++j) hi[j] = (bf16_t)a[j];
            *(bf16x8*)&xh[(size_t)node * HID + c0] = hi;
        }
    }
}

// ---------------------------------------------------------------------------
// Pooling: pooled[g][c] += x3[n][c] for batch[n]==g (batch sorted, run-flush)
// ---------------------------------------------------------------------------
__global__ void pool_k(const float* __restrict__ x3, const int* __restrict__ batch,
                       float* __restrict__ pooled) {
    int t  = threadIdx.x;            // 256: cols t and t+256
    int n0 = blockIdx.x * 20;
    int nend = min(n0 + 20, N_NODES);
    float acc0 = 0.f, acc1 = 0.f;
    int cur = -1;
    for (int n = n0; n < nend; ++n) {
        int g = batch[n];
        if (g != cur) {
            if (cur >= 0) {
                atomicAdd(&pooled[cur * HID + t], acc0);
                atomicAdd(&pooled[cur * HID + t + 256], acc1);
            }
            cur = g; acc0 = 0.f; acc1 = 0.f;
        }
        acc0 += x3[(size_t)n * HID + t];
        acc1 += x3[(size_t)n * HID + t + 256];
    }
    if (cur >= 0) {
        atomicAdd(&pooled[cur * HID + t], acc0);
        atomicAdd(&pooled[cur * HID + t + 256], acc1);
    }
}

// ---------------------------------------------------------------------------
// Head: logits = pooled @ lin_w + lin_b ; log_softmax. One wave per graph.
// ---------------------------------------------------------------------------
__global__ __launch_bounds__(64) void head_k(const float* __restrict__ pooled,
                                             const float* __restrict__ lw,
                                             const float* __restrict__ lb,
                                             float* __restrict__ out) {
    int g = blockIdx.x, l = threadIdx.x;
    float lg[10];
#pragma unroll
    for (int c = 0; c < N_CLASSES; ++c) {
        float s = 0.f;
        for (int k = l; k < HID; k += 64) s += pooled[g * HID + k] * lw[k * N_CLASSES + c];
        for (int o2 = 32; o2 > 0; o2 >>= 1) s += __shfl_down(s, o2);
        lg[c] = s;
    }
    if (l == 0) {
        float mx = -1e30f;
#pragma unroll
        for (int c = 0; c < N_CLASSES; ++c) { lg[c] += lb[c]; mx = fmaxf(mx, lg[c]); }
        float se = 0.f;
#pragma unroll
        for (int c = 0; c < N_CLASSES; ++c) se += expf(lg[c] - mx);
        float lse = logf(se);
#pragma unroll
        for (int c = 0; c < N_CLASSES; ++c) out[g * N_CLASSES + c] = lg[c] - mx - lse;
    }
}

// ---------------------------------------------------------------------------
extern "C" void kernel_launch(void* const* d_in, const int* in_sizes, int n_in,
                              void* d_out, int out_size, void* d_ws, size_t ws_size,
                              hipStream_t stream) {
    const float* x     = (const float*)d_in[0];
    const int*   ei    = (const int*)d_in[1];
    const int*   batch = (const int*)d_in[2];
    const float* Ws    = (const float*)d_in[3];
    const float* bs    = (const float*)d_in[4];
    const float* lw    = (const float*)d_in[5];
    const float* lb    = (const float*)d_in[6];
    float*       out   = (float*)d_out;
    const int E = in_sizes[1] / 2;
    const int* erow = ei;       // edge_index[0] = source
    const int* ecol = ei + E;   // edge_index[1] = target (aggregation index)

    char* p = (char*)d_ws;
    auto take = [&](size_t bytes) {
        char* q = p;
        p += (bytes + 255) & ~(size_t)255;
        return q;
    };
    bf16_t* xh    = (bf16_t*)take((size_t)MPAD * HID * 2);
    bf16_t* hh    = (bf16_t*)take((size_t)MPAD * HID * 2);
    float*  x3    = (float*) take((size_t)N_NODES * HID * 4);
    bf16_t* whT   = (bf16_t*)take((size_t)3 * HID * HID * 2);
    float*  dinv  = (float*) take((size_t)N_NODES * 4);
    int*    cnt   = (int*)   take((size_t)N_NODES * 4);
    int*    off   = (int*)   take((size_t)(N_NODES + 1) * 4);
    int*    cur   = (int*)   take((size_t)N_NODES * 4);
    int2*   epk   = (int2*)  take((size_t)E * 8 + 64);   // +pad for int4 tail read
    float*  pooled= (float*) take((size_t)N_GRAPHS * HID * 4);

    const int cdeg_b = (E + 255) / 256;
    zero_k<<<40, 256, 0, stream>>>(cnt, cur, xh + (size_t)N_NODES * HID, pooled);
    setup_k<<<CVX_B + TRW_B + cdeg_b, 256, 0, stream>>>(
        x, xh, Ws, whT, ecol, cnt, E);
    scan_k<<<1, 1024, 0, stream>>>(cnt, off, dinv);
    scatter_k<<<cdeg_b, 256, 0, stream>>>(erow, ecol, off, cur, dinv, epk, E);

    for (int lyr = 0; lyr < 3; ++lyr) {
        gemm3<<<dim3(4, 158), 256, 0, stream>>>(
            xh, whT + (size_t)lyr * HID * HID, hh);
        if (lyr < 2)
            agg_k<false><<<N_NODES / 2, 256, 0, stream>>>(
                hh, off, epk, dinv, bs + lyr * HID, xh, nullptr);
        else
            agg_k<true><<<N_NODES / 2, 256, 0, stream>>>(
                hh, off, epk, dinv, bs + lyr * HID, nullptr, x3);
    }
    pool_k<<<500, 256, 0, stream>>>(x3, batch, pooled);
    head_k<<<N_GRAPHS, 64, 0, stream>>>(pooled, lw, lb, out);
}